// Round 4
// baseline (90.442 us; speedup 1.0000x reference)
//
#include <hip/hip_runtime.h>

// Problem constants (fixed by the reference)
#define BATCH   8192
#define GROUPS  512
#define ARITY   3
#define OUT_DIM 16
#define NV      27          // 3^3 vertices
#define XCOLS   (GROUPS*ARITY)      // 1536
#define OCOLS   (GROUPS*OUT_DIM)    // 8192

// Tiling: block = 256 threads = 4 waves.
//   lane covers (group gl = t>>3, output-half oh = t&7): 2 floats of the 16.
//   block covers 32 groups (blockIdx.y) x 64 batches (blockIdx.x).
#define BTILE 64
#define GTILE 32

// LDS actually used: 64*96 floats = 24 KiB. Padded to 40 KiB so exactly
// 4 blocks/CU are resident (160/40): 2048 blocks = 8/CU = exactly 2 full
// rounds -> 100% packing (vs 8-over-5 = 80% when VGPR allowed 5 waves).
#define XS_USED   (BTILE * GTILE * ARITY)       // 6144 floats
#define XS_PADDED (40960 / 4)                   // 10240 floats = 40 KiB

typedef float f32x2 __attribute__((ext_vector_type(2)));

__global__ __launch_bounds__(256, 4) void lattice_interp_kernel(
    const float* __restrict__ X,
    const float* __restrict__ P,
    float* __restrict__ out)
{
    __shared__ float xs[XS_PADDED];   // first XS_USED floats used, linear

    const int t  = threadIdx.x;
    const int b0 = blockIdx.x * BTILE;
    const int gb = blockIdx.y * GTILE;

    // ---- stage X tile rows [b0,b0+64) cols [gb*3, gb*3+96) into LDS.
    // flat float4 index f = t + k*256 ; r = f/24, c = f%24 ;
    // LDS dest = f*16B (linear => matches global_load_lds wave-uniform+lane*16)
    {
        const float* src_base = X + (size_t)b0 * XCOLS + gb * ARITY;
        #pragma unroll
        for (int k = 0; k < 6; ++k) {
            const int f = t + k * 256;
            const int r = f / 24;
            const int c = f % 24;
            const float* src = src_base + (size_t)r * XCOLS + c * 4;
            __builtin_amdgcn_global_load_lds(
                (const __attribute__((address_space(1))) void*)src,
                (__attribute__((address_space(3))) void*)&xs[f * 4],
                16, 0, 0);
        }
    }

    // ---- this lane's param slice: 27 x float2 (54 VGPR), reused for all 64 b.
    const int gl = t >> 3;     // group-local 0..31
    const int oh = t & 7;      // which float2 of the 16 outputs
    const int g  = gb + gl;

    f32x2 p[NV];
    {
        const f32x2* P2 = reinterpret_cast<const f32x2*>(P) + (size_t)g * (NV * 8) + oh;
        #pragma unroll
        for (int v = 0; v < NV; ++v) p[v] = P2[v * 8];
    }

    __syncthreads();   // drains global_load_lds

    // compute-read banks: 8 lanes/group broadcast one addr; 8 addrs stride 3
    // floats -> banks {0,3,..,21}, conflict-free.
    const int xcol = gl * ARITY;
    // out col within block = gl*16 + oh*2 == 2*t  -> each wave writes one
    // contiguous aligned 512B segment per b.
    float* outp = out + (size_t)b0 * OCOLS + gb * OUT_DIM + t * 2;

    #pragma unroll 4
    for (int b = 0; b < BTILE; ++b) {
        const float x0 = xs[b * (GTILE * ARITY) + xcol + 0];
        const float x1 = xs[b * (GTILE * ARITY) + xcol + 1];
        const float x2 = xs[b * (GTILE * ARITY) + xcol + 2];

        // hat basis over {-1,0,+1}: d=0 -> relu(-x), 1 -> 1-|x|, 2 -> relu(x)
        const float w0a[3] = { fmaxf(-x0, 0.0f), 1.0f - fabsf(x0), fmaxf(x0, 0.0f) };
        const float w1a[3] = { fmaxf(-x1, 0.0f), 1.0f - fabsf(x1), fmaxf(x1, 0.0f) };
        const float w2a[3] = { fmaxf(-x2, 0.0f), 1.0f - fabsf(x2), fmaxf(x2, 0.0f) };

        // factorized tensor-product contraction:
        // B1[i]=sum_d0 w0[d0]*p[3i+d0]; B2[d2]=sum_d1 w1[d1]*B1[d1+3d2];
        // acc = sum_d2 w2[d2]*B2[d2].   v = d0 + 3*d1 + 9*d2 = 3*i + d0.
        f32x2 acc = { 0.0f, 0.0f };
        #pragma unroll
        for (int d2 = 0; d2 < 3; ++d2) {
            f32x2 b2 = { 0.0f, 0.0f };
            #pragma unroll
            for (int d1 = 0; d1 < 3; ++d1) {
                const int i = d1 + 3 * d2;
                f32x2 b1 = w0a[0] * p[3*i] + w0a[1] * p[3*i+1] + w0a[2] * p[3*i+2];
                b2 += w1a[d1] * b1;
            }
            acc += w2a[d2] * b2;
        }

        *reinterpret_cast<f32x2*>(outp + (size_t)b * OCOLS) = acc;
    }
}

extern "C" void kernel_launch(void* const* d_in, const int* in_sizes, int n_in,
                              void* d_out, int out_size, void* d_ws, size_t ws_size,
                              hipStream_t stream) {
    const float* X = (const float*)d_in[0];   // [8192, 1536] f32
    const float* P = (const float*)d_in[1];   // [512, 27, 16] f32
    float* out = (float*)d_out;               // [8192, 8192] f32

    dim3 grid(BATCH / BTILE, GROUPS / GTILE); // 128 x 16
    dim3 block(256);
    lattice_interp_kernel<<<grid, block, 0, stream>>>(X, P, out);
}

// Round 5
// 81.358 us; speedup vs baseline: 1.1116x; 1.1116x over previous
//
#include <hip/hip_runtime.h>

// Problem constants (fixed by the reference)
#define BATCH   8192
#define GROUPS  512
#define ARITY   3
#define OUT_DIM 16
#define NV      27          // 3^3 vertices
#define XCOLS   (GROUPS*ARITY)      // 1536
#define OCOLS   (GROUPS*OUT_DIM)    // 8192

// Tiling: block = 256 threads = 4 waves.
//   lane covers (group gl = t>>3, output-half oh = t&7): 2 floats of the 16.
//   block covers 32 groups (blockIdx.y) x 32 batches (blockIdx.x).
// Occupancy is the proven lever (3w->91.6us, 5w->78.7, 4w->90.4):
// launch_bounds(256,6) caps VGPR at 85 (p=54 + ~26 working set fits),
// LDS down to 12 KiB so VGPR is the only limiter -> 6 waves/SIMD.
#define BTILE 32
#define GTILE 32

typedef float f32x2 __attribute__((ext_vector_type(2)));

__global__ __launch_bounds__(256, 6) void lattice_interp_kernel(
    const float* __restrict__ X,
    const float* __restrict__ P,
    float* __restrict__ out)
{
    __shared__ float xs[BTILE * GTILE * ARITY];   // 32*96 floats = 12 KiB, linear

    const int t  = threadIdx.x;
    const int b0 = blockIdx.x * BTILE;
    const int gb = blockIdx.y * GTILE;

    // ---- stage X tile rows [b0,b0+32) cols [gb*3, gb*3+96) into LDS.
    // flat float4 index f = t + k*256 ; r = f/24, c = f%24 ;
    // LDS dest = f*16B (linear => matches global_load_lds wave-uniform+lane*16)
    {
        const float* src_base = X + (size_t)b0 * XCOLS + gb * ARITY;
        #pragma unroll
        for (int k = 0; k < 3; ++k) {
            const int f = t + k * 256;
            const int r = f / 24;
            const int c = f % 24;
            const float* src = src_base + (size_t)r * XCOLS + c * 4;
            __builtin_amdgcn_global_load_lds(
                (const __attribute__((address_space(1))) void*)src,
                (__attribute__((address_space(3))) void*)&xs[f * 4],
                16, 0, 0);
        }
    }

    // ---- this lane's param slice: 27 x float2 (54 VGPR), reused for all 32 b.
    const int gl = t >> 3;     // group-local 0..31
    const int oh = t & 7;      // which float2 of the 16 outputs
    const int g  = gb + gl;

    f32x2 p[NV];
    {
        const f32x2* P2 = reinterpret_cast<const f32x2*>(P) + (size_t)g * (NV * 8) + oh;
        #pragma unroll
        for (int v = 0; v < NV; ++v) p[v] = P2[v * 8];
    }

    __syncthreads();   // drains global_load_lds

    // compute-read banks: 8 lanes/group broadcast one addr; addrs stride 3
    // floats -> conflict-free broadcast.
    const int xcol = gl * ARITY;
    // out col within block = gl*16 + oh*2 == 2*t  -> each wave writes one
    // contiguous aligned 512B segment per b.
    float* outp = out + (size_t)b0 * OCOLS + gb * OUT_DIM + t * 2;

    #pragma unroll 2
    for (int b = 0; b < BTILE; ++b) {
        const float x0 = xs[b * (GTILE * ARITY) + xcol + 0];
        const float x1 = xs[b * (GTILE * ARITY) + xcol + 1];
        const float x2 = xs[b * (GTILE * ARITY) + xcol + 2];

        // hat basis over {-1,0,+1}: d=0 -> relu(-x), 1 -> 1-|x|, 2 -> relu(x)
        const float w0a[3] = { fmaxf(-x0, 0.0f), 1.0f - fabsf(x0), fmaxf(x0, 0.0f) };
        const float w1a[3] = { fmaxf(-x1, 0.0f), 1.0f - fabsf(x1), fmaxf(x1, 0.0f) };
        const float w2a[3] = { fmaxf(-x2, 0.0f), 1.0f - fabsf(x2), fmaxf(x2, 0.0f) };

        // factorized tensor-product contraction:
        // B1[i]=sum_d0 w0[d0]*p[3i+d0]; B2[d2]=sum_d1 w1[d1]*B1[d1+3d2];
        // acc = sum_d2 w2[d2]*B2[d2].   v = d0 + 3*d1 + 9*d2 = 3*i + d0.
        f32x2 acc = { 0.0f, 0.0f };
        #pragma unroll
        for (int d2 = 0; d2 < 3; ++d2) {
            f32x2 b2 = { 0.0f, 0.0f };
            #pragma unroll
            for (int d1 = 0; d1 < 3; ++d1) {
                const int i = d1 + 3 * d2;
                f32x2 b1 = w0a[0] * p[3*i] + w0a[1] * p[3*i+1] + w0a[2] * p[3*i+2];
                b2 += w1a[d1] * b1;
            }
            acc += w2a[d2] * b2;
        }

        __builtin_nontemporal_store(acc, reinterpret_cast<f32x2*>(outp + (size_t)b * OCOLS));
    }
}

extern "C" void kernel_launch(void* const* d_in, const int* in_sizes, int n_in,
                              void* d_out, int out_size, void* d_ws, size_t ws_size,
                              hipStream_t stream) {
    const float* X = (const float*)d_in[0];   // [8192, 1536] f32
    const float* P = (const float*)d_in[1];   // [512, 27, 16] f32
    float* out = (float*)d_out;               // [8192, 8192] f32

    dim3 grid(BATCH / BTILE, GROUPS / GTILE); // 256 x 16 = 4096 blocks
    dim3 block(256);
    lattice_interp_kernel<<<grid, block, 0, stream>>>(X, P, out);
}

// Round 6
// 75.997 us; speedup vs baseline: 1.1901x; 1.0706x over previous
//
#include <hip/hip_runtime.h>

// Problem constants (fixed by the reference)
#define BATCH   8192
#define GROUPS  512
#define ARITY   3
#define OUT_DIM 16
#define NV      27          // 3^3 vertices
#define XCOLS   (GROUPS*ARITY)      // 1536
#define OCOLS   (GROUPS*OUT_DIM)    // 8192

// Structure: only the 8 corners of the containing cell have nonzero basis
// (one of relu(-x)/relu(x) is exactly 0 per dim). Params live in LDS
// (runtime vertex index), freeing ~54 VGPRs -> 8 waves/SIMD.
// Block = 256 thr = 4 waves; wave = 8 groups x 8 output-halves, owns 16 b.
// LDS: params 8 groups x 436 words (pad: gl*436%32 distinct for gl=0..7)
//      + X tile 64b x 24 floats. Total 20096 B -> exactly 8 blocks/CU.
#define BTILE 64
#define GTILE 8
#define PSTRIDE 436     // 432 + 4 pad words

typedef float f32x2 __attribute__((ext_vector_type(2)));

__global__ __launch_bounds__(256, 8) void lattice_interp_kernel(
    const float* __restrict__ X,
    const float* __restrict__ P,
    float* __restrict__ out)
{
    __shared__ float xs[BTILE * GTILE * ARITY];   // 1536 floats = 6 KiB, linear
    __shared__ float ps[GTILE * PSTRIDE];         // 3488 floats = 13952 B

    const int t  = threadIdx.x;
    const int b0 = blockIdx.x * BTILE;
    const int g0 = blockIdx.y * GTILE;

    // ---- stage X tile rows [b0,b0+64) cols [g0*3, g0*3+24) into LDS.
    // 384 float4; f = t + k*256; row r = f/6, col c = f%6 (6 float4/row).
    {
        const float* src_base = X + (size_t)b0 * XCOLS + g0 * ARITY;
        #pragma unroll
        for (int k = 0; k < 2; ++k) {
            const int f = t + k * 256;
            if (f < 384) {
                const int r = f / 6;
                const int c = f % 6;
                const float* src = src_base + (size_t)r * XCOLS + c * 4;
                __builtin_amdgcn_global_load_lds(
                    (const __attribute__((address_space(1))) void*)src,
                    (__attribute__((address_space(3))) void*)&xs[f * 4],
                    16, 0, 0);
            }
        }
    }

    // ---- stage params for 8 groups (3456 contiguous floats = 864 float4)
    // into padded LDS: group gl at word gl*436 (8 distinct bank offsets).
    {
        const float4* src = reinterpret_cast<const float4*>(P + (size_t)g0 * (NV * OUT_DIM));
        #pragma unroll
        for (int k = 0; k < 4; ++k) {
            const int f = t + k * 256;
            if (f < 864) {
                const float4 v = src[f];
                const int pgl = f / 108;          // 108 float4 per group
                const int rem = f - pgl * 108;
                *reinterpret_cast<float4*>(&ps[pgl * PSTRIDE + rem * 4]) = v;
            }
        }
    }

    __syncthreads();   // drains global_load_lds (vmcnt) + ds_writes (lgkmcnt)

    const int wave = t >> 6;
    const int gl   = (t & 63) >> 3;   // group-local 0..7
    const int oh   = t & 7;           // which float2 of the 16 outputs

    // loop-invariant bases
    const float* pb = ps + gl * PSTRIDE + oh * 2;          // + vb*16 words at runtime
    const float* xb = xs + gl * ARITY;
    float* outp = out + (size_t)b0 * OCOLS + (size_t)g0 * OUT_DIM + (t & 63) * 2;

    #pragma unroll 2
    for (int i = 0; i < 16; ++i) {
        const int b = wave * 16 + i;
        const float x0 = xb[b * (GTILE * ARITY) + 0];
        const float x1 = xb[b * (GTILE * ARITY) + 1];
        const float x2 = xb[b * (GTILE * ARITY) + 2];

        // containing cell per dim: x<0 -> [-1,0] (s=0), else [0,1] (s=1);
        // lower/upper hat weights (the dropped third weight is exactly 0)
        const bool n0 = x0 < 0.0f, n1 = x1 < 0.0f, n2 = x2 < 0.0f;
        const float wl0 = n0 ? -x0        : 1.0f - x0;
        const float wh0 = n0 ? 1.0f + x0  : x0;
        const float wl1 = n1 ? -x1        : 1.0f - x1;
        const float wh1 = n1 ? 1.0f + x1  : x1;
        const float wl2 = n2 ? -x2        : 1.0f - x2;
        const float wh2 = n2 ? 1.0f + x2  : x2;
        const int   vb  = (n0 ? 0 : 1) + 3 * (n1 ? 0 : 1) + 9 * (n2 ? 0 : 1);

        // 8 corner weights (tensor product of the 2 nonzero weights/dim)
        const float wA = wl0 * wl1, wB = wh0 * wl1, wC = wl0 * wh1, wD = wh0 * wh1;
        const float c000 = wA * wl2, c100 = wB * wl2, c010 = wC * wl2, c110 = wD * wl2;
        const float c001 = wA * wh2, c101 = wB * wh2, c011 = wC * wh2, c111 = wD * wh2;

        // one runtime base + 8 immediate-offset ds_read_b64
        // vertex offset (c0 + 3c1 + 9c2) in f32x2 units: *8
        const f32x2* pp = reinterpret_cast<const f32x2*>(pb + vb * 16);
        f32x2 acc =  c000 * pp[0];
        acc += c100 * pp[8];
        acc += c010 * pp[24];
        acc += c110 * pp[32];
        acc += c001 * pp[72];
        acc += c101 * pp[80];
        acc += c011 * pp[96];
        acc += c111 * pp[104];

        __builtin_nontemporal_store(acc, reinterpret_cast<f32x2*>(outp + (size_t)b * OCOLS));
    }
}

extern "C" void kernel_launch(void* const* d_in, const int* in_sizes, int n_in,
                              void* d_out, int out_size, void* d_ws, size_t ws_size,
                              hipStream_t stream) {
    const float* X = (const float*)d_in[0];   // [8192, 1536] f32
    const float* P = (const float*)d_in[1];   // [512, 27, 16] f32
    float* out = (float*)d_out;               // [8192, 8192] f32

    dim3 grid(BATCH / BTILE, GROUPS / GTILE); // 128 x 64 = 8192 blocks
    dim3 block(256);
    lattice_interp_kernel<<<grid, block, 0, stream>>>(X, P, out);
}